// Round 9
// baseline (795.226 us; speedup 1.0000x reference)
//
#include <hip/hip_runtime.h>
#include <stdint.h>

#define TPB 1024
#define HSZ 32768
#define NCH 8              // chunks per row
#define CHF4 1024          // float4 per chunk (16 KB); CHF4 == TPB
#define NW (TPB / 64)      // 16 waves
#define NBIN 2048          // level-1 bins: key bits [31:21]
#define CAP 1024           // candidate capacity (threshold bin ~40-80 for N(0,1))

// LDS-only barrier: orders LDS (lgkmcnt) but leaves global/DMA ops in flight.
#define BARRIER() do { \
    asm volatile("s_waitcnt lgkmcnt(0)" ::: "memory"); \
    __builtin_amdgcn_s_barrier(); \
} while (0)

// Counted vmem wait (T4): waits oldest (outstanding-n) vmem ops; sched_barrier
// stops the scheduler from moving memory ops across the wait point.
#define WAITVM(n) do { \
    asm volatile("s_waitcnt vmcnt(" #n ")" ::: "memory"); \
    __builtin_amdgcn_sched_barrier(0); \
} while (0)

// order-preserving float->uint key: bigger float => bigger key
__device__ __forceinline__ uint32_t f2k(float f) {
    uint32_t u = __float_as_uint(f);
    return u ^ (0x80000000u | (uint32_t)(-(int32_t)(u >> 31)));
}

struct Sm {
    float4 row[NCH * CHF4];     // 128 KB resident row (slots recycled per-thread)
    uint32_t hist[2][NBIN];     // 16 KB ping-pong level-1 histograms
    uint32_t cand_key[CAP];     // 4 KB
    uint32_t cand_col[CAP];     // 4 KB
    uint32_t wtot[NW];
    uint32_t bin, rem, eqcnt, ncand, chunk_base;
};                              // ~155.8 KB (<160 KB/CU)

// DMA one 16 KB chunk: global -> LDS slot c. Thread t's 16 B are written and
// later read ONLY by thread t -> staging needs no barriers, only per-wave vmcnt.
__device__ __forceinline__ void dma_chunk(const float* __restrict__ xrow, Sm& sm,
                                          int c, int t) {
    const uint32_t* g = (const uint32_t*)xrow + (size_t)c * (CHF4 * 4) + (size_t)t * 4;
    uint32_t* l = (uint32_t*)(sm.row + c * CHF4 + t);
    __builtin_amdgcn_global_load_lds(
        (const __attribute__((address_space(1))) uint32_t*)g,
        (__attribute__((address_space(3))) uint32_t*)l,
        16, 0, 0);
}

// Block-wide suffix select over hist[h] (descending bins = larger values).
// Finds bin B with count(>B) < need <= count(>=B); writes bin, rem, eqcnt.
__device__ __forceinline__ void select2048(Sm& sm, int h, uint32_t need, int t) {
    const int lane = t & 63, wid = t >> 6;
    const uint32_t b0 = sm.hist[h][t * 2];
    const uint32_t b1 = sm.hist[h][t * 2 + 1];
    const uint32_t pt = b0 + b1;
    uint32_t pre = pt;  // wave suffix-inclusive scan
#pragma unroll
    for (int off = 1; off < 64; off <<= 1) {
        uint32_t n = (uint32_t)__shfl_down((int)pre, off, 64);
        if (lane + off < 64) pre += n;
    }
    if (lane == 0) sm.wtot[wid] = pre;
    BARRIER();
    uint32_t wsuf = 0;
    for (int w = wid + 1; w < NW; ++w) wsuf += sm.wtot[w];
    const uint32_t Sincl = pre + wsuf;
    const uint32_t Sexcl = Sincl - pt;
    if (Sexcl < need && Sincl >= need) {
        if (Sexcl + b1 >= need) { sm.bin = (uint32_t)(t * 2 + 1); sm.rem = need - Sexcl; sm.eqcnt = b1; }
        else { sm.bin = (uint32_t)(t * 2); sm.rem = need - Sexcl - b1; sm.eqcnt = b0; }
    }
    BARRIER();
}

// one histogram chunk (ds_read own 16B + 4 LDS atomics); hb is runtime 0/1
#define A_CHUNK(c) do { \
    float4 v = sm.row[(c) * CHF4 + t]; \
    atomicAdd(&sm.hist[hb][f2k(v.x) >> 21], 1u); \
    atomicAdd(&sm.hist[hb][f2k(v.y) >> 21], 1u); \
    atomicAdd(&sm.hist[hb][f2k(v.z) >> 21], 1u); \
    atomicAdd(&sm.hist[hb][f2k(v.w) >> 21], 1u); \
} while (0)

__global__ __launch_bounds__(TPB) void topk_scatter_kernel(
    const float* __restrict__ x,
    const int* __restrict__ kp,
    float* __restrict__ out,
    int nrows)
{
    __shared__ Sm sm;
    const int t = threadIdx.x;
    const int gs = (int)gridDim.x;
    const int ki = kp[0];

    if (ki <= 0 || ki >= HSZ) {  // degenerate: all zeros or identity copy
        for (int r = (int)blockIdx.x; r < nrows; r += gs) {
            const float4* xr4 = reinterpret_cast<const float4*>(x + (size_t)r * HSZ);
            float4* o4 = reinterpret_cast<float4*>(out + (size_t)r * HSZ);
#pragma unroll
            for (int c = 0; c < NCH; ++c) {
                float4 o;
                if (ki <= 0) { o.x = o.y = o.z = o.w = 0.0f; }
                else o = xr4[c * CHF4 + t];
                o4[c * CHF4 + t] = o;
            }
        }
        return;
    }
    const uint32_t k = (uint32_t)ki;

    int r = (int)blockIdx.x;
    if (r >= nrows) return;

    // prologue: issue first row's 8 DMAs, zero both hist buffers
#pragma unroll
    for (int c = 0; c < NCH; ++c) dma_chunk(x + (size_t)r * HSZ, sm, c, t);
    for (int i = t; i < 2 * NBIN; i += TPB) ((uint32_t*)sm.hist)[i] = 0u;
    BARRIER();

    int hb = 0;
    bool fresh = true;   // fresh: only 8 DMAs outstanding (prologue / post-fallback)

    for (;;) {
        // ===== phase A: chunk-pipelined histogram under DMA arrival =====
        // steady stream per wave from prior B2: S0,D0,S1,D1,...,S7,D7 (16 ops);
        // chunk c needs Dc retired -> wait vmcnt(2*(7-c)). In-order retirement
        // (m135) makes each wait exact; over-wait is safe, under-wait impossible
        // because sched_barrier pins the B2 emission order.
        if (fresh) {
            WAITVM(7); A_CHUNK(0); WAITVM(6); A_CHUNK(1);
            WAITVM(5); A_CHUNK(2); WAITVM(4); A_CHUNK(3);
            WAITVM(3); A_CHUNK(4); WAITVM(2); A_CHUNK(5);
            WAITVM(1); A_CHUNK(6); WAITVM(0); A_CHUNK(7);
            fresh = false;
        } else {
            WAITVM(14); A_CHUNK(0); WAITVM(12); A_CHUNK(1);
            WAITVM(10); A_CHUNK(2); WAITVM(8);  A_CHUNK(3);
            WAITVM(6);  A_CHUNK(4); WAITVM(4);  A_CHUNK(5);
            WAITVM(2);  A_CHUNK(6); WAITVM(0);  A_CHUNK(7);
        }
        BARRIER();   // hist complete

        // ===== select level-1 bin (2 internal barriers publish bin/rem/ncand) =====
        if (t == 0) sm.ncand = 0u;
        select2048(sm, hb, k, t);
        const uint32_t B1 = sm.bin;
        const uint32_t need2 = sm.rem;

        // ===== B1: zero other hist + candidate compaction =====
        sm.hist[hb ^ 1][t] = 0u;
        sm.hist[hb ^ 1][t + TPB] = 0u;
#pragma unroll
        for (int c = 0; c < NCH; ++c) {
            float4 v = sm.row[c * CHF4 + t];
            float vals[4] = { v.x, v.y, v.z, v.w };
#pragma unroll
            for (int e = 0; e < 4; ++e) {
                uint32_t key = f2k(vals[e]);
                if ((key >> 21) == B1) {
                    uint32_t pos = atomicAdd(&sm.ncand, 1u);
                    if (pos < CAP) {
                        sm.cand_key[pos] = key;
                        sm.cand_col[pos] = (uint32_t)((c * CHF4 + t) * 4 + e);
                    }
                }
            }
        }
        BARRIER();   // compaction + hist-zero visible
        const uint32_t C = sm.ncand;

        const int rn = r + gs;
        const float* xnext = (rn < nrows) ? (x + (size_t)rn * HSZ) : nullptr;
        float4* out4 = reinterpret_cast<float4*>(out + (size_t)r * HSZ);

        if (C <= CAP) {
            // ===== refine: barrier-free MSB radix over candidate keys =====
            // all lanes/waves compute identically (reads synced by prior barrier)
            const int lane = t & 63;
            uint32_t pref = B1 << 21;
            uint32_t needR = need2;
            for (int bit = 20; bit >= 0; --bit) {
                const uint32_t thr = (pref >> bit) | 1u;
                uint32_t cnt = 0;
                for (uint32_t i = (uint32_t)lane; i < C; i += 64)
                    cnt += ((sm.cand_key[i] >> bit) == thr) ? 1u : 0u;
#pragma unroll
                for (int off = 32; off; off >>= 1)
                    cnt += (uint32_t)__shfl_xor((int)cnt, off, 64);
                if (cnt >= needR) pref |= (1u << bit); else needR -= cnt;
            }
            const uint32_t K = pref;
            const uint32_t eqneed = needR;
            uint32_t ce = 0;
            for (uint32_t i = (uint32_t)lane; i < C; i += 64)
                ce += (sm.cand_key[i] == K) ? 1u : 0u;
#pragma unroll
            for (int off = 32; off; off >>= 1)
                ce += (uint32_t)__shfl_xor((int)ce, off, 64);
            const bool simple = (ce == eqneed);

            // ===== B2: single final store per word + per-chunk DMA recycle =====
#pragma unroll
            for (int c = 0; c < NCH; ++c) {
                float4 v = sm.row[c * CHF4 + t];
                float vals[4] = { v.x, v.y, v.z, v.w };
                float ov[4];
#pragma unroll
                for (int e = 0; e < 4; ++e) {
                    uint32_t key = f2k(vals[e]);
                    bool take = key > K;
                    if (key == K) {
                        if (simple) take = true;
                        else {  // exact tie-break: lowest columns win
                            uint32_t col = (uint32_t)((c * CHF4 + t) * 4 + e);
                            uint32_t rank = 0;
                            for (uint32_t m = 0; m < C; ++m)
                                if (sm.cand_key[m] == K && sm.cand_col[m] < col) ++rank;
                            take = (rank < eqneed);
                        }
                    }
                    ov[e] = take ? vals[e] : 0.0f;
                }
                float4 o; o.x = ov[0]; o.y = ov[1]; o.z = ov[2]; o.w = ov[3];
                out4[c * CHF4 + t] = o;
                __builtin_amdgcn_sched_barrier(0);     // pin S_c before D_c
                if (xnext) dma_chunk(xnext, sm, c, t); // recycle own 16B of slot c
                __builtin_amdgcn_sched_barrier(0);     // pin chunk order
            }
        } else {
            // ===== fallback (C > CAP; ~never for Gaussian): row LDS intact =====
            // level 2: key bits [20:10] into hist[hb^1] (zeroed in B1)
#pragma unroll
            for (int c = 0; c < NCH; ++c) {
                float4 v = sm.row[c * CHF4 + t];
                float vals[4] = { v.x, v.y, v.z, v.w };
#pragma unroll
                for (int e = 0; e < 4; ++e) {
                    uint32_t key = f2k(vals[e]);
                    if ((key >> 21) == B1) atomicAdd(&sm.hist[hb ^ 1][(key >> 10) & 0x7FFu], 1u);
                }
            }
            BARRIER();
            select2048(sm, hb ^ 1, need2, t);
            const uint32_t B2b = sm.bin;
            const uint32_t need3 = sm.rem;
            // zero hist[hb] (dirty from level 1), then level 3: bits [9:0]
            sm.hist[hb][t] = 0u; sm.hist[hb][t + TPB] = 0u;
            BARRIER();
            const uint32_t pref2 = (B1 << 11) | B2b;   // top 22 key bits
#pragma unroll
            for (int c = 0; c < NCH; ++c) {
                float4 v = sm.row[c * CHF4 + t];
                float vals[4] = { v.x, v.y, v.z, v.w };
#pragma unroll
                for (int e = 0; e < 4; ++e) {
                    uint32_t key = f2k(vals[e]);
                    if ((key >> 10) == pref2) atomicAdd(&sm.hist[hb][key & 0x3FFu], 1u);
                }
            }
            BARRIER();
            select2048(sm, hb, need3, t);   // bins >=1024 are zero
            const uint32_t K = (pref2 << 10) | sm.bin;
            const uint32_t eqneed = sm.rem;
            const uint32_t eqcnt = sm.eqcnt;

            if (eqcnt == eqneed) {
#pragma unroll
                for (int c = 0; c < NCH; ++c) {
                    float4 v = sm.row[c * CHF4 + t];
                    float ov[4] = {
                        (f2k(v.x) >= K) ? v.x : 0.0f, (f2k(v.y) >= K) ? v.y : 0.0f,
                        (f2k(v.z) >= K) ? v.z : 0.0f, (f2k(v.w) >= K) ? v.w : 0.0f };
                    float4 o; o.x = ov[0]; o.y = ov[1]; o.z = ov[2]; o.w = ov[3];
                    out4[c * CHF4 + t] = o;
                }
            } else {
                // ordered selection among ==K by lowest column, chunk-by-chunk
                if (t == 0) sm.chunk_base = 0u;
                BARRIER();
                const int lane = t & 63;
                const int wid = t >> 6;
                for (int c = 0; c < NCH; ++c) {
                    float4 v = sm.row[c * CHF4 + t];
                    float vals[4] = { v.x, v.y, v.z, v.w };
                    uint32_t keys[4];
                    uint32_t e0 = 0;
#pragma unroll
                    for (int e = 0; e < 4; ++e) { keys[e] = f2k(vals[e]); e0 += (keys[e] == K) ? 1u : 0u; }
                    uint32_t pre = e0;
                    for (int off = 1; off < 64; off <<= 1) {
                        uint32_t n = (uint32_t)__shfl_up((int)pre, off, 64);
                        if (lane >= off) pre += n;
                    }
                    if (lane == 63) sm.wtot[wid] = pre;
                    BARRIER();
                    uint32_t before = sm.chunk_base + (pre - e0);
                    for (int w = 0; w < wid; ++w) before += sm.wtot[w];
                    float ov[4];
#pragma unroll
                    for (int e = 0; e < 4; ++e) {
                        bool take = keys[e] > K;
                        if (keys[e] == K) { take = (before < eqneed); ++before; }
                        ov[e] = take ? vals[e] : 0.0f;
                    }
                    float4 o; o.x = ov[0]; o.y = ov[1]; o.z = ov[2]; o.w = ov[3];
                    out4[c * CHF4 + t] = o;
                    BARRIER();
                    if (t == 0) {
                        uint32_t s2 = sm.chunk_base;
#pragma unroll
                        for (int w = 0; w < NW; ++w) s2 += sm.wtot[w];
                        sm.chunk_base = s2;
                    }
                    BARRIER();
                }
            }
            // issue next row's DMAs after all stores; restart with fresh waits
            if (xnext) {
#pragma unroll
                for (int c = 0; c < NCH; ++c) dma_chunk(xnext, sm, c, t);
            }
            for (int i = t; i < 2 * NBIN; i += TPB) ((uint32_t*)sm.hist)[i] = 0u;
            BARRIER();
            fresh = true;
        }

        if (rn >= nrows) break;
        r = rn;
        hb ^= 1;
    }
}

extern "C" void kernel_launch(void* const* d_in, const int* in_sizes, int n_in,
                              void* d_out, int out_size, void* d_ws, size_t ws_size,
                              hipStream_t stream) {
    const float* x = (const float*)d_in[0];
    const int* kp = (const int*)d_in[1];
    float* out = (float*)d_out;
    const int total = in_sizes[0];
    const int rows = total / HSZ;        // 8192
    int grid = rows < 256 ? rows : 256;  // 1 persistent block per CU (LDS-bound)
    topk_scatter_kernel<<<grid, TPB, 0, stream>>>(x, kp, out, rows);
}

// Round 10
// 607.374 us; speedup vs baseline: 1.3093x; 1.3093x over previous
//
#include <hip/hip_runtime.h>
#include <stdint.h>

#define TPB 1024
#define HSZ 32768
#define NCH 8              // chunks per row
#define CHF4 1024          // float4 per chunk (16 KB); CHF4 == TPB
#define NW (TPB / 64)      // 16 waves
#define NBIN 2048          // level-1 bins: key bits [31:21]
#define CAP 1024           // candidate capacity (threshold bin ~334 for N(0,1))

// LDS-only barrier: orders LDS (lgkmcnt) but leaves global/DMA ops in flight.
#define BARRIER() do { \
    asm volatile("s_waitcnt lgkmcnt(0)" ::: "memory"); \
    __builtin_amdgcn_s_barrier(); \
} while (0)

// Counted vmem wait (T4); sched_barrier pins memory-op order around it.
#define WAITVM(n) do { \
    asm volatile("s_waitcnt vmcnt(" #n ")" ::: "memory"); \
    __builtin_amdgcn_sched_barrier(0); \
} while (0)

// order-preserving float->uint key: bigger float => bigger key
__device__ __forceinline__ uint32_t f2k(float f) {
    uint32_t u = __float_as_uint(f);
    return u ^ (0x80000000u | (uint32_t)(-(int32_t)(u >> 31)));
}

struct Sm {
    float4 row[NCH * CHF4];     // 128 KB resident row (per-thread 16B ownership)
    uint32_t hist[2][NBIN];     // 16 KB: hist0 = A + level-3; hist1 = level-2
    uint32_t cand_key[CAP];     // 4 KB
    uint32_t cand_col[CAP];     // 4 KB
    uint32_t wtot[NW];
    uint32_t bin, rem, eqcnt, ncand, chunk_base;
};                              // ~152 KB (<160 KB/CU)

// DMA one 16 KB chunk: global -> LDS slot c. Thread t's 16 B are written and
// read ONLY by thread t (everywhere) -> staging needs no barriers, only vmcnt.
__device__ __forceinline__ void dma_chunk(const float* __restrict__ xrow, Sm& sm,
                                          int c, int t) {
    const uint32_t* g = (const uint32_t*)xrow + (size_t)c * (CHF4 * 4) + (size_t)t * 4;
    uint32_t* l = (uint32_t*)(sm.row + c * CHF4 + t);
    __builtin_amdgcn_global_load_lds(
        (const __attribute__((address_space(1))) uint32_t*)g,
        (__attribute__((address_space(3))) uint32_t*)l,
        16, 0, 0);
}

// Block-wide suffix select over hist[h] (descending bins = larger values).
// Finds bin B with count(>B) < need <= count(>=B); writes bin, rem, eqcnt.
// Work is PARTITIONED across threads (2 bins each), never redundant.
__device__ __forceinline__ void select2048(Sm& sm, int h, uint32_t need, int t) {
    const int lane = t & 63, wid = t >> 6;
    const uint32_t b0 = sm.hist[h][t * 2];
    const uint32_t b1 = sm.hist[h][t * 2 + 1];
    const uint32_t pt = b0 + b1;
    uint32_t pre = pt;  // wave suffix-inclusive scan
#pragma unroll
    for (int off = 1; off < 64; off <<= 1) {
        uint32_t n = (uint32_t)__shfl_down((int)pre, off, 64);
        if (lane + off < 64) pre += n;
    }
    if (lane == 0) sm.wtot[wid] = pre;
    BARRIER();
    uint32_t wsuf = 0;
    for (int w = wid + 1; w < NW; ++w) wsuf += sm.wtot[w];
    const uint32_t Sincl = pre + wsuf;
    const uint32_t Sexcl = Sincl - pt;
    if (Sexcl < need && Sincl >= need) {
        if (Sexcl + b1 >= need) { sm.bin = (uint32_t)(t * 2 + 1); sm.rem = need - Sexcl; sm.eqcnt = b1; }
        else { sm.bin = (uint32_t)(t * 2); sm.rem = need - Sexcl - b1; sm.eqcnt = b0; }
    }
    BARRIER();
}

// one histogram chunk: ds_read own 16B + 4 LDS atomics into hist0
#define A_CHUNK(c) do { \
    float4 v = sm.row[(c) * CHF4 + t]; \
    atomicAdd(&sm.hist[0][f2k(v.x) >> 21], 1u); \
    atomicAdd(&sm.hist[0][f2k(v.y) >> 21], 1u); \
    atomicAdd(&sm.hist[0][f2k(v.z) >> 21], 1u); \
    atomicAdd(&sm.hist[0][f2k(v.w) >> 21], 1u); \
} while (0)

__global__ __launch_bounds__(TPB) void topk_scatter_kernel(
    const float* __restrict__ x,
    const int* __restrict__ kp,
    float* __restrict__ out,
    int nrows)
{
    __shared__ Sm sm;
    const int t = threadIdx.x;
    const int gs = (int)gridDim.x;
    const int ki = kp[0];

    if (ki <= 0 || ki >= HSZ) {  // degenerate: all zeros or identity copy
        for (int r = (int)blockIdx.x; r < nrows; r += gs) {
            const float4* xr4 = reinterpret_cast<const float4*>(x + (size_t)r * HSZ);
            float4* o4 = reinterpret_cast<float4*>(out + (size_t)r * HSZ);
#pragma unroll
            for (int c = 0; c < NCH; ++c) {
                float4 o;
                if (ki <= 0) { o.x = o.y = o.z = o.w = 0.0f; }
                else o = xr4[c * CHF4 + t];
                o4[c * CHF4 + t] = o;
            }
        }
        return;
    }
    const uint32_t k = (uint32_t)ki;

    int r = (int)blockIdx.x;
    if (r >= nrows) return;

    // prologue: issue first row's 8 DMAs, zero both hist buffers
#pragma unroll
    for (int c = 0; c < NCH; ++c) dma_chunk(x + (size_t)r * HSZ, sm, c, t);
    for (int i = t; i < 2 * NBIN; i += TPB) ((uint32_t*)sm.hist)[i] = 0u;
    BARRIER();

    bool fresh = true;   // fresh: only 8 DMAs outstanding (prologue/post-fallback)

    for (;;) {
        // ===== phase A: chunk-pipelined histogram under DMA arrival =====
        // steady per-wave stream from prior B2: S0,D0,...,S7,D7 (16 ops, pinned);
        // chunk c needs D_c retired -> vmcnt(14-2c). In-order retirement (m135).
        if (fresh) {
            WAITVM(7); A_CHUNK(0); WAITVM(6); A_CHUNK(1);
            WAITVM(5); A_CHUNK(2); WAITVM(4); A_CHUNK(3);
            WAITVM(3); A_CHUNK(4); WAITVM(2); A_CHUNK(5);
            WAITVM(1); A_CHUNK(6); WAITVM(0); A_CHUNK(7);
            fresh = false;
        } else {
            WAITVM(14); A_CHUNK(0); WAITVM(12); A_CHUNK(1);
            WAITVM(10); A_CHUNK(2); WAITVM(8);  A_CHUNK(3);
            WAITVM(6);  A_CHUNK(4); WAITVM(4);  A_CHUNK(5);
            WAITVM(2);  A_CHUNK(6); WAITVM(0);  A_CHUNK(7);
        }
        BARRIER();   // hist0 complete

        // ===== select level-1 bin (bits [31:21]) =====
        if (t == 0) sm.ncand = 0u;
        select2048(sm, 0, k, t);
        const uint32_t B1 = sm.bin;
        const uint32_t need2 = sm.rem;

        // ===== B1: zero hist0 (consumed) + candidate compaction =====
        sm.hist[0][t] = 0u;
        sm.hist[0][t + TPB] = 0u;
#pragma unroll
        for (int c = 0; c < NCH; ++c) {
            float4 v = sm.row[c * CHF4 + t];
            float vals[4] = { v.x, v.y, v.z, v.w };
#pragma unroll
            for (int e = 0; e < 4; ++e) {
                uint32_t key = f2k(vals[e]);
                if ((key >> 21) == B1) {
                    uint32_t pos = atomicAdd(&sm.ncand, 1u);
                    if (pos < CAP) {
                        sm.cand_key[pos] = key;
                        sm.cand_col[pos] = (uint32_t)((c * CHF4 + t) * 4 + e);
                    }
                }
            }
        }
        BARRIER();
        const uint32_t C = sm.ncand;

        const int rn = r + gs;
        const float* xnext = (rn < nrows) ? (x + (size_t)rn * HSZ) : nullptr;
        float4* out4 = reinterpret_cast<float4*>(out + (size_t)r * HSZ);

        // ===== refine: level-2 (bits [20:10]) then level-3 (bits [9:0]) =====
        // Partitioned hist atomics (O(C/TPB) per thread), never redundant.
        uint32_t K, eqneed, eqcnt;
        if (C <= CAP) {
            for (uint32_t i = t; i < C; i += TPB)
                atomicAdd(&sm.hist[1][(sm.cand_key[i] >> 10) & 0x7FFu], 1u);
            BARRIER();
            select2048(sm, 1, need2, t);
            const uint32_t pref2 = (B1 << 11) | sm.bin;   // key >> 10
            const uint32_t need3 = sm.rem;
            for (uint32_t i = t; i < C; i += TPB) {
                uint32_t key = sm.cand_key[i];
                if ((key >> 10) == pref2) atomicAdd(&sm.hist[0][key & 0x3FFu], 1u);
            }
            BARRIER();
            select2048(sm, 0, need3, t);   // bins >= 1024 are zero
            K = (pref2 << 10) | sm.bin;
            eqneed = sm.rem;
            eqcnt = sm.eqcnt;
        } else {
            // overflow (~never for Gaussian): refine from full LDS row (intact)
#pragma unroll
            for (int c = 0; c < NCH; ++c) {
                float4 v = sm.row[c * CHF4 + t];
                float vals[4] = { v.x, v.y, v.z, v.w };
#pragma unroll
                for (int e = 0; e < 4; ++e) {
                    uint32_t key = f2k(vals[e]);
                    if ((key >> 21) == B1) atomicAdd(&sm.hist[1][(key >> 10) & 0x7FFu], 1u);
                }
            }
            BARRIER();
            select2048(sm, 1, need2, t);
            const uint32_t pref2 = (B1 << 11) | sm.bin;
            const uint32_t need3 = sm.rem;
#pragma unroll
            for (int c = 0; c < NCH; ++c) {
                float4 v = sm.row[c * CHF4 + t];
                float vals[4] = { v.x, v.y, v.z, v.w };
#pragma unroll
                for (int e = 0; e < 4; ++e) {
                    uint32_t key = f2k(vals[e]);
                    if ((key >> 10) == pref2) atomicAdd(&sm.hist[0][key & 0x3FFu], 1u);
                }
            }
            BARRIER();
            select2048(sm, 0, need3, t);
            K = (pref2 << 10) | sm.bin;
            eqneed = sm.rem;
            eqcnt = sm.eqcnt;
        }
        const bool simple = (eqcnt == eqneed);

        // ===== B2: zero both hists; single final store + per-chunk DMA recycle =====
        sm.hist[0][t] = 0u; sm.hist[0][t + TPB] = 0u;
        sm.hist[1][t] = 0u; sm.hist[1][t + TPB] = 0u;
        if (simple || C <= CAP) {
#pragma unroll
            for (int c = 0; c < NCH; ++c) {
                float4 v = sm.row[c * CHF4 + t];
                float vals[4] = { v.x, v.y, v.z, v.w };
                float ov[4];
#pragma unroll
                for (int e = 0; e < 4; ++e) {
                    uint32_t key = f2k(vals[e]);
                    bool take = key > K;
                    if (key == K) {
                        if (simple) take = true;
                        else {  // exact tie-break vs candidate list: lowest cols win
                            uint32_t col = (uint32_t)((c * CHF4 + t) * 4 + e);
                            uint32_t rank = 0;
                            for (uint32_t m = 0; m < C; ++m)
                                if (sm.cand_key[m] == K && sm.cand_col[m] < col) ++rank;
                            take = (rank < eqneed);
                        }
                    }
                    ov[e] = take ? vals[e] : 0.0f;
                }
                float4 o; o.x = ov[0]; o.y = ov[1]; o.z = ov[2]; o.w = ov[3];
                out4[c * CHF4 + t] = o;
                __builtin_amdgcn_sched_barrier(0);     // pin S_c ...
                if (xnext) dma_chunk(xnext, sm, c, t); // ... before D_c
                __builtin_amdgcn_sched_barrier(0);     // pin chunk order
            }
        } else {
            // overflow + ties (astronomically rare): ordered selection among ==K
            // by lowest column, chunk-by-chunk; DMAs issued afterwards, grouped.
            if (t == 0) sm.chunk_base = 0u;
            BARRIER();
            const int lane = t & 63;
            const int wid = t >> 6;
            for (int c = 0; c < NCH; ++c) {
                float4 v = sm.row[c * CHF4 + t];
                float vals[4] = { v.x, v.y, v.z, v.w };
                uint32_t keys[4];
                uint32_t e0 = 0;
#pragma unroll
                for (int e = 0; e < 4; ++e) { keys[e] = f2k(vals[e]); e0 += (keys[e] == K) ? 1u : 0u; }
                uint32_t pre = e0;
                for (int off = 1; off < 64; off <<= 1) {
                    uint32_t n = (uint32_t)__shfl_up((int)pre, off, 64);
                    if (lane >= off) pre += n;
                }
                if (lane == 63) sm.wtot[wid] = pre;
                BARRIER();
                uint32_t before = sm.chunk_base + (pre - e0);
                for (int w = 0; w < wid; ++w) before += sm.wtot[w];
                float ov[4];
#pragma unroll
                for (int e = 0; e < 4; ++e) {
                    bool take = keys[e] > K;
                    if (keys[e] == K) { take = (before < eqneed); ++before; }
                    ov[e] = take ? vals[e] : 0.0f;
                }
                float4 o; o.x = ov[0]; o.y = ov[1]; o.z = ov[2]; o.w = ov[3];
                out4[c * CHF4 + t] = o;
                BARRIER();
                if (t == 0) {
                    uint32_t s2 = sm.chunk_base;
#pragma unroll
                    for (int w = 0; w < NW; ++w) s2 += sm.wtot[w];
                    sm.chunk_base = s2;
                }
                BARRIER();
            }
            if (xnext) {
#pragma unroll
                for (int c = 0; c < NCH; ++c) dma_chunk(xnext, sm, c, t);
            }
            fresh = true;
        }
        BARRIER();   // hist zeros (and any tail state) visible before next A

        if (rn >= nrows) break;
        r = rn;
    }
}

extern "C" void kernel_launch(void* const* d_in, const int* in_sizes, int n_in,
                              void* d_out, int out_size, void* d_ws, size_t ws_size,
                              hipStream_t stream) {
    const float* x = (const float*)d_in[0];
    const int* kp = (const int*)d_in[1];
    float* out = (float*)d_out;
    const int total = in_sizes[0];
    const int rows = total / HSZ;        // 8192
    int grid = rows < 256 ? rows : 256;  // 1 persistent block per CU (LDS-bound)
    topk_scatter_kernel<<<grid, TPB, 0, stream>>>(x, kp, out, rows);
}